// Round 2
// baseline (86.909 us; speedup 1.0000x reference)
//
#include <hip/hip_runtime.h>
#include <math.h>

#define PI_F 3.14159265358979323846f

__device__ __forceinline__ float dot4(const float4 a, const float4 b) {
    return a.x * b.x + a.y * b.y + a.z * b.z + a.w * b.w;
}

// ---- quantum gate helpers: all indices compile-time after unroll ----
template<int P>
__device__ __forceinline__ void rx_gate(float (&ar)[16], float (&ai)[16], float c, float s) {
#pragma unroll
    for (int m = 0; m < 8; ++m) {
        const int i0 = ((m >> P) << (P + 1)) | (m & ((1 << P) - 1));
        const int i1 = i0 | (1 << P);
        const float a0r = ar[i0], a0i = ai[i0], a1r = ar[i1], a1i = ai[i1];
        // [c, -i s; -i s, c]
        ar[i0] = c * a0r + s * a1i;
        ai[i0] = c * a0i - s * a1r;
        ar[i1] = c * a1r + s * a0i;
        ai[i1] = c * a1i - s * a0r;
    }
}

template<int P>
__device__ __forceinline__ void ry_gate(float (&ar)[16], float (&ai)[16], float c, float s) {
#pragma unroll
    for (int m = 0; m < 8; ++m) {
        const int i0 = ((m >> P) << (P + 1)) | (m & ((1 << P) - 1));
        const int i1 = i0 | (1 << P);
        const float a0r = ar[i0], a0i = ai[i0], a1r = ar[i1], a1i = ai[i1];
        // [c, -s; s, c] (real)
        ar[i0] = c * a0r - s * a1r;
        ai[i0] = c * a0i - s * a1i;
        ar[i1] = s * a0r + c * a1r;
        ai[i1] = s * a0i + c * a1i;
    }
}

template<int PC, int PT>
__device__ __forceinline__ void cnot_gate(float (&ar)[16], float (&ai)[16]) {
#pragma unroll
    for (int i = 0; i < 16; ++i) {
        if ((i & (1 << PC)) && !(i & (1 << PT))) {
            const int j = i | (1 << PT);
            float tr = ar[i]; ar[i] = ar[j]; ar[j] = tr;
            float ti = ai[i]; ai[i] = ai[j]; ai[j] = ti;
        }
    }
}

__global__ __launch_bounds__(256, 4)
void hybrid_qnn_kernel(const float* __restrict__ x,
                       const float* __restrict__ W_red,
                       const float* __restrict__ b_red,
                       const float* __restrict__ qw,
                       const float* __restrict__ W_out,
                       const float* __restrict__ b_out,
                       float* __restrict__ out,
                       int B)
{
    __shared__ float h_lds[64][4];
    __shared__ float qc_lds[8];
    __shared__ float qs_lds[8];
    __shared__ float outStage[640];

    const int t = threadIdx.x;
    const int lane = t & 63;
    const int wave = t >> 6;
    const long long blockBase = (long long)blockIdx.x * 64;

    if (t < 8) {
        const float a = 0.5f * qw[t];
        qc_lds[t] = cosf(a);
        qs_lds[t] = sinf(a);
    }

    // ---- W_red into registers (scaled by 1/255), split-K over 64 lanes ----
    const float inv255 = 1.0f / 255.0f;
    float4 Wl[3][4];
#pragma unroll
    for (int c = 0; c < 3; ++c) {
#pragma unroll
        for (int j = 0; j < 4; ++j) {
            const float4 w = *(const float4*)(W_red + j * 784 + 4 * (lane + 64 * c));
            Wl[c][j] = make_float4(w.x * inv255, w.y * inv255, w.z * inv255, w.w * inv255);
        }
    }
    float4 Wr[4];
#pragma unroll
    for (int j = 0; j < 4; ++j) Wr[j] = make_float4(0.f, 0.f, 0.f, 0.f);
    if (lane < 4) {
#pragma unroll
        for (int j = 0; j < 4; ++j) {
            const float4 w = *(const float4*)(W_red + j * 784 + 4 * (192 + lane));
            Wr[j] = make_float4(w.x * inv255, w.y * inv255, w.z * inv255, w.w * inv255);
        }
    }
    const float br0 = b_red[0], br1 = b_red[1], br2 = b_red[2], br3 = b_red[3];

    // ---- phase A: each wave computes h for its 16 samples ----
#pragma unroll 2
    for (int q = 0; q < 16; ++q) {
        const int srow = wave * 16 + q;
        const long long samp = blockBase + srow;
        if (samp < B) {
            const float4* xr4 = (const float4*)(x + (size_t)samp * 784);
            const float4 x0 = xr4[lane];
            const float4 x1 = xr4[lane + 64];
            const float4 x2 = xr4[lane + 128];
            float4 x3 = make_float4(0.f, 0.f, 0.f, 0.f);
            if (lane < 4) x3 = xr4[192 + lane];

            float s0 = dot4(x0, Wl[0][0]) + dot4(x1, Wl[1][0]) + dot4(x2, Wl[2][0]) + dot4(x3, Wr[0]);
            float s1 = dot4(x0, Wl[0][1]) + dot4(x1, Wl[1][1]) + dot4(x2, Wl[2][1]) + dot4(x3, Wr[1]);
            float s2 = dot4(x0, Wl[0][2]) + dot4(x1, Wl[1][2]) + dot4(x2, Wl[2][2]) + dot4(x3, Wr[2]);
            float s3 = dot4(x0, Wl[0][3]) + dot4(x1, Wl[1][3]) + dot4(x2, Wl[2][3]) + dot4(x3, Wr[3]);

#pragma unroll
            for (int m = 32; m >= 1; m >>= 1) {
                s0 += __shfl_xor(s0, m);
                s1 += __shfl_xor(s1, m);
                s2 += __shfl_xor(s2, m);
                s3 += __shfl_xor(s3, m);
            }
            if (lane == 0) {
                h_lds[srow][0] = s0 + br0;
                h_lds[srow][1] = s1 + br1;
                h_lds[srow][2] = s2 + br2;
                h_lds[srow][3] = s3 + br3;
            }
        }
    }
    __syncthreads();

    // ---- phase B: per-thread 4-qubit statevector sim for one sample ----
    if (t < 64 && blockBase + t < B) {
        const float ang0 = tanhf(h_lds[t][0]) * PI_F;
        const float ang1 = tanhf(h_lds[t][1]) * PI_F;
        const float ang2 = tanhf(h_lds[t][2]) * PI_F;
        const float ang3 = tanhf(h_lds[t][3]) * PI_F;
        const float c0 = cosf(0.5f * ang0), sn0 = sinf(0.5f * ang0);
        const float c1 = cosf(0.5f * ang1), sn1 = sinf(0.5f * ang1);
        const float c2 = cosf(0.5f * ang2), sn2 = sinf(0.5f * ang2);
        const float c3 = cosf(0.5f * ang3), sn3 = sinf(0.5f * ang3);

        float ar[16], ai[16];
#pragma unroll
        for (int i = 0; i < 16; ++i) { ar[i] = 0.f; ai[i] = 0.f; }
        ar[0] = 1.f;

        // RX encoding: wire w -> bit position 3-w (wire 0 = MSB)
        rx_gate<3>(ar, ai, c0, sn0);
        rx_gate<2>(ar, ai, c1, sn1);
        rx_gate<1>(ar, ai, c2, sn2);
        rx_gate<0>(ar, ai, c3, sn3);

#pragma unroll
        for (int layer = 0; layer < 2; ++layer) {
            const int k0 = layer * 4;
            ry_gate<3>(ar, ai, qc_lds[k0 + 0], qs_lds[k0 + 0]);
            ry_gate<2>(ar, ai, qc_lds[k0 + 1], qs_lds[k0 + 1]);
            ry_gate<1>(ar, ai, qc_lds[k0 + 2], qs_lds[k0 + 2]);
            ry_gate<0>(ar, ai, qc_lds[k0 + 3], qs_lds[k0 + 3]);
            // CNOT ring (control wire, target wire): (0,1),(1,2),(2,3),(3,0)
            cnot_gate<3, 2>(ar, ai);
            cnot_gate<2, 1>(ar, ai);
            cnot_gate<1, 0>(ar, ai);
            cnot_gate<0, 3>(ar, ai);
        }

        float pr[16];
#pragma unroll
        for (int i = 0; i < 16; ++i) pr[i] = ar[i] * ar[i] + ai[i] * ai[i];

        float ev[4];
#pragma unroll
        for (int w = 0; w < 4; ++w) {
            const int p = 3 - w;
            float e = 0.f;
#pragma unroll
            for (int i = 0; i < 16; ++i) e += (i & (1 << p)) ? -pr[i] : pr[i];
            ev[w] = e;
        }

#pragma unroll
        for (int n = 0; n < 10; ++n) {
            float o = b_out[n];
#pragma unroll
            for (int j = 0; j < 4; ++j) o += ev[j] * W_out[n * 4 + j];
            outStage[t * 10 + n] = o;
        }
    }
    __syncthreads();

    // ---- coalesced output store ----
    const long long outBase = (long long)blockIdx.x * 640;
    const long long outTotal = (long long)B * 10;
#pragma unroll
    for (int i = t; i < 640; i += 256) {
        const long long oi = outBase + i;
        if (oi < outTotal) out[oi] = outStage[i];
    }
}

extern "C" void kernel_launch(void* const* d_in, const int* in_sizes, int n_in,
                              void* d_out, int out_size, void* d_ws, size_t ws_size,
                              hipStream_t stream) {
    const float* x      = (const float*)d_in[0];
    const float* W_red  = (const float*)d_in[1];
    const float* b_red  = (const float*)d_in[2];
    const float* qw     = (const float*)d_in[3];
    const float* W_out  = (const float*)d_in[4];
    const float* b_out  = (const float*)d_in[5];
    float* out = (float*)d_out;

    const int B = in_sizes[0] / 784;
    const int grid = (B + 63) / 64;
    hipLaunchKernelGGL(hybrid_qnn_kernel, dim3(grid), dim3(256), 0, stream,
                       x, W_red, b_red, qw, W_out, b_out, out, B);
}

// Round 3
// 81.195 us; speedup vs baseline: 1.0704x; 1.0704x over previous
//
#include <hip/hip_runtime.h>
#include <math.h>

#define PI_F 3.14159265358979323846f

__device__ __forceinline__ float dot4(const float4 a, const float4 b) {
    return a.x * b.x + a.y * b.y + a.z * b.z + a.w * b.w;
}

// ---- quantum gate helpers: all indices compile-time after unroll ----
template<int P>
__device__ __forceinline__ void rx_gate(float (&ar)[16], float (&ai)[16], float c, float s) {
#pragma unroll
    for (int m = 0; m < 8; ++m) {
        const int i0 = ((m >> P) << (P + 1)) | (m & ((1 << P) - 1));
        const int i1 = i0 | (1 << P);
        const float a0r = ar[i0], a0i = ai[i0], a1r = ar[i1], a1i = ai[i1];
        ar[i0] = c * a0r + s * a1i;
        ai[i0] = c * a0i - s * a1r;
        ar[i1] = c * a1r + s * a0i;
        ai[i1] = c * a1i - s * a0r;
    }
}

template<int P>
__device__ __forceinline__ void ry_gate(float (&ar)[16], float (&ai)[16], float c, float s) {
#pragma unroll
    for (int m = 0; m < 8; ++m) {
        const int i0 = ((m >> P) << (P + 1)) | (m & ((1 << P) - 1));
        const int i1 = i0 | (1 << P);
        const float a0r = ar[i0], a0i = ai[i0], a1r = ar[i1], a1i = ai[i1];
        ar[i0] = c * a0r - s * a1r;
        ai[i0] = c * a0i - s * a1i;
        ar[i1] = s * a0r + c * a1r;
        ai[i1] = s * a0i + c * a1i;
    }
}

template<int PC, int PT>
__device__ __forceinline__ void cnot_gate(float (&ar)[16], float (&ai)[16]) {
#pragma unroll
    for (int i = 0; i < 16; ++i) {
        if ((i & (1 << PC)) && !(i & (1 << PT))) {
            const int j = i | (1 << PT);
            float tr = ar[i]; ar[i] = ar[j]; ar[j] = tr;
            float ti = ai[i]; ai[i] = ai[j]; ai[j] = ti;
        }
    }
}

// pack-reduce: s0..s3 (per-lane partials) -> lane j in {0..3} holds total s_j.
// 7 shfls total: 2-level 4x4 transpose-combine + 4-level butterfly.
__device__ __forceinline__ float pack_reduce4(int lane, float s0, float s1, float s2, float s3) {
    const bool b1 = (lane & 1) != 0;
    const bool b2 = (lane & 2) != 0;
    const float u01 = (b1 ? s1 : s0) + __shfl_xor(b1 ? s0 : s1, 1);
    const float u23 = (b1 ? s3 : s2) + __shfl_xor(b1 ? s2 : s3, 1);
    float v = (b2 ? u23 : u01) + __shfl_xor(b2 ? u01 : u23, 2);
    v += __shfl_xor(v, 4);
    v += __shfl_xor(v, 8);
    v += __shfl_xor(v, 16);
    v += __shfl_xor(v, 32);
    return v;  // lane&3 == j  =>  v = total s_j
}

__global__ __launch_bounds__(256, 4)
void hybrid_qnn_kernel(const float* __restrict__ x,
                       const float* __restrict__ W_red,
                       const float* __restrict__ b_red,
                       const float* __restrict__ qw,
                       const float* __restrict__ W_out,
                       const float* __restrict__ b_out,
                       float* __restrict__ out,
                       int B)
{
    __shared__ float h_lds[64][4];
    __shared__ float qc_lds[8];
    __shared__ float qs_lds[8];
    __shared__ float outStage[640];

    const int t = threadIdx.x;
    const int lane = t & 63;
    const int wave = t >> 6;
    const long long blockBase = (long long)blockIdx.x * 64;
    const long long wbase = blockBase + wave * 16;

    if (t < 8) {
        const float a = 0.5f * qw[t];
        qc_lds[t] = cosf(a);
        qs_lds[t] = sinf(a);
    }

    const float inv255 = 1.0f / 255.0f;

    // ---- main weights (floats 0..767), split-K over 64 lanes, pre-scaled ----
    float4 Wl[3][4];
#pragma unroll
    for (int c = 0; c < 3; ++c) {
#pragma unroll
        for (int j = 0; j < 4; ++j) {
            const float4 w = *(const float4*)(W_red + j * 784 + 4 * (lane + 64 * c));
            Wl[c][j] = make_float4(w.x * inv255, w.y * inv255, w.z * inv255, w.w * inv255);
        }
    }
    const float br0 = b_red[0], br1 = b_red[1], br2 = b_red[2], br3 = b_red[3];

    // ---- tail prepass: floats 768..783 for this wave's 16 samples ----
    // lane = s*4 + c : sample s (0..15), chunk c (0..3)
    {
        const int s = lane >> 2;
        const int c = lane & 3;
        const long long samp = wbase + s;
        float4 wt[4];
#pragma unroll
        for (int j = 0; j < 4; ++j) {
            const float4 w = *(const float4*)(W_red + j * 784 + 768 + 4 * c);
            wt[j] = make_float4(w.x * inv255, w.y * inv255, w.z * inv255, w.w * inv255);
        }
        float4 xt = make_float4(0.f, 0.f, 0.f, 0.f);
        if (samp < B) xt = *(const float4*)(x + (size_t)samp * 784 + 768 + 4 * c);
        float d0 = dot4(xt, wt[0]);
        float d1 = dot4(xt, wt[1]);
        float d2 = dot4(xt, wt[2]);
        float d3 = dot4(xt, wt[3]);
        // reduce over c (lane bits 0..1)
        d0 += __shfl_xor(d0, 1); d0 += __shfl_xor(d0, 2);
        d1 += __shfl_xor(d1, 1); d1 += __shfl_xor(d1, 2);
        d2 += __shfl_xor(d2, 1); d2 += __shfl_xor(d2, 2);
        d3 += __shfl_xor(d3, 1); d3 += __shfl_xor(d3, 2);
        if (c == 0 && samp < B) {
            const int srow = wave * 16 + s;
            h_lds[srow][0] = d0 + br0;
            h_lds[srow][1] = d1 + br1;
            h_lds[srow][2] = d2 + br2;
            h_lds[srow][3] = d3 + br3;
        }
    }

    // ---- phase A: 3 coalesced 1KB loads/sample, software-pipelined ----
    if (wbase + 16 <= B) {
        const float* xbase = x + (size_t)wbase * 784;
        float4 c0 = *(const float4*)(xbase + 4 * lane);
        float4 c1 = *(const float4*)(xbase + 4 * (lane + 64));
        float4 c2 = *(const float4*)(xbase + 4 * (lane + 128));
#pragma unroll
        for (int q = 0; q < 16; ++q) {
            const float4 x0 = c0, x1 = c1, x2 = c2;
            if (q < 15) {
                const float* nb = xbase + (size_t)(q + 1) * 784;
                c0 = *(const float4*)(nb + 4 * lane);
                c1 = *(const float4*)(nb + 4 * (lane + 64));
                c2 = *(const float4*)(nb + 4 * (lane + 128));
            }
            const float s0 = dot4(x0, Wl[0][0]) + dot4(x1, Wl[1][0]) + dot4(x2, Wl[2][0]);
            const float s1 = dot4(x0, Wl[0][1]) + dot4(x1, Wl[1][1]) + dot4(x2, Wl[2][1]);
            const float s2 = dot4(x0, Wl[0][2]) + dot4(x1, Wl[1][2]) + dot4(x2, Wl[2][2]);
            const float s3 = dot4(x0, Wl[0][3]) + dot4(x1, Wl[1][3]) + dot4(x2, Wl[2][3]);
            const float v = pack_reduce4(lane, s0, s1, s2, s3);
            if (lane < 4) h_lds[wave * 16 + q][lane] += v;
        }
    } else {
        for (int q = 0; q < 16; ++q) {
            const long long samp = wbase + q;
            if (samp >= B) break;
            const float* xb = x + (size_t)samp * 784;
            const float4 x0 = *(const float4*)(xb + 4 * lane);
            const float4 x1 = *(const float4*)(xb + 4 * (lane + 64));
            const float4 x2 = *(const float4*)(xb + 4 * (lane + 128));
            const float s0 = dot4(x0, Wl[0][0]) + dot4(x1, Wl[1][0]) + dot4(x2, Wl[2][0]);
            const float s1 = dot4(x0, Wl[0][1]) + dot4(x1, Wl[1][1]) + dot4(x2, Wl[2][1]);
            const float s2 = dot4(x0, Wl[0][2]) + dot4(x1, Wl[1][2]) + dot4(x2, Wl[2][2]);
            const float s3 = dot4(x0, Wl[0][3]) + dot4(x1, Wl[1][3]) + dot4(x2, Wl[2][3]);
            const float v = pack_reduce4(lane, s0, s1, s2, s3);
            if (lane < 4) h_lds[wave * 16 + q][lane] += v;
        }
    }
    __syncthreads();

    // ---- phase B: per-thread 4-qubit statevector sim for one sample ----
    if (t < 64 && blockBase + t < B) {
        const float ang0 = tanhf(h_lds[t][0]) * PI_F;
        const float ang1 = tanhf(h_lds[t][1]) * PI_F;
        const float ang2 = tanhf(h_lds[t][2]) * PI_F;
        const float ang3 = tanhf(h_lds[t][3]) * PI_F;
        const float c0 = cosf(0.5f * ang0), sn0 = sinf(0.5f * ang0);
        const float c1 = cosf(0.5f * ang1), sn1 = sinf(0.5f * ang1);
        const float c2 = cosf(0.5f * ang2), sn2 = sinf(0.5f * ang2);
        const float c3 = cosf(0.5f * ang3), sn3 = sinf(0.5f * ang3);

        float ar[16], ai[16];
#pragma unroll
        for (int i = 0; i < 16; ++i) { ar[i] = 0.f; ai[i] = 0.f; }
        ar[0] = 1.f;

        // RX encoding: wire w -> bit position 3-w (wire 0 = MSB)
        rx_gate<3>(ar, ai, c0, sn0);
        rx_gate<2>(ar, ai, c1, sn1);
        rx_gate<1>(ar, ai, c2, sn2);
        rx_gate<0>(ar, ai, c3, sn3);

#pragma unroll
        for (int layer = 0; layer < 2; ++layer) {
            const int k0 = layer * 4;
            ry_gate<3>(ar, ai, qc_lds[k0 + 0], qs_lds[k0 + 0]);
            ry_gate<2>(ar, ai, qc_lds[k0 + 1], qs_lds[k0 + 1]);
            ry_gate<1>(ar, ai, qc_lds[k0 + 2], qs_lds[k0 + 2]);
            ry_gate<0>(ar, ai, qc_lds[k0 + 3], qs_lds[k0 + 3]);
            // CNOT ring (control wire, target wire): (0,1),(1,2),(2,3),(3,0)
            cnot_gate<3, 2>(ar, ai);
            cnot_gate<2, 1>(ar, ai);
            cnot_gate<1, 0>(ar, ai);
            cnot_gate<0, 3>(ar, ai);
        }

        float pr[16];
#pragma unroll
        for (int i = 0; i < 16; ++i) pr[i] = ar[i] * ar[i] + ai[i] * ai[i];

        float ev[4];
#pragma unroll
        for (int w = 0; w < 4; ++w) {
            const int p = 3 - w;
            float e = 0.f;
#pragma unroll
            for (int i = 0; i < 16; ++i) e += (i & (1 << p)) ? -pr[i] : pr[i];
            ev[w] = e;
        }

#pragma unroll
        for (int n = 0; n < 10; ++n) {
            float o = b_out[n];
#pragma unroll
            for (int j = 0; j < 4; ++j) o += ev[j] * W_out[n * 4 + j];
            outStage[t * 10 + n] = o;
        }
    }
    __syncthreads();

    // ---- coalesced output store ----
    const long long outBase = (long long)blockIdx.x * 640;
    const long long outTotal = (long long)B * 10;
#pragma unroll
    for (int i = t; i < 640; i += 256) {
        const long long oi = outBase + i;
        if (oi < outTotal) out[oi] = outStage[i];
    }
}

extern "C" void kernel_launch(void* const* d_in, const int* in_sizes, int n_in,
                              void* d_out, int out_size, void* d_ws, size_t ws_size,
                              hipStream_t stream) {
    const float* x      = (const float*)d_in[0];
    const float* W_red  = (const float*)d_in[1];
    const float* b_red  = (const float*)d_in[2];
    const float* qw     = (const float*)d_in[3];
    const float* W_out  = (const float*)d_in[4];
    const float* b_out  = (const float*)d_in[5];
    float* out = (float*)d_out;

    const int B = in_sizes[0] / 784;
    const int grid = (B + 63) / 64;
    hipLaunchKernelGGL(hybrid_qnn_kernel, dim3(grid), dim3(256), 0, stream,
                       x, W_red, b_red, qw, W_out, b_out, out, B);
}

// Round 4
// 80.782 us; speedup vs baseline: 1.0758x; 1.0051x over previous
//
#include <hip/hip_runtime.h>
#include <math.h>

#define PI_F 3.14159265358979323846f

__device__ __forceinline__ float dot4(const float4 a, const float4 b) {
    return a.x * b.x + a.y * b.y + a.z * b.z + a.w * b.w;
}

// ---- quantum gate helpers: all indices compile-time after unroll ----
template<int P>
__device__ __forceinline__ void rx_gate(float (&ar)[16], float (&ai)[16], float c, float s) {
#pragma unroll
    for (int m = 0; m < 8; ++m) {
        const int i0 = ((m >> P) << (P + 1)) | (m & ((1 << P) - 1));
        const int i1 = i0 | (1 << P);
        const float a0r = ar[i0], a0i = ai[i0], a1r = ar[i1], a1i = ai[i1];
        ar[i0] = c * a0r + s * a1i;
        ai[i0] = c * a0i - s * a1r;
        ar[i1] = c * a1r + s * a0i;
        ai[i1] = c * a1i - s * a0r;
    }
}

template<int P>
__device__ __forceinline__ void ry_gate(float (&ar)[16], float (&ai)[16], float c, float s) {
#pragma unroll
    for (int m = 0; m < 8; ++m) {
        const int i0 = ((m >> P) << (P + 1)) | (m & ((1 << P) - 1));
        const int i1 = i0 | (1 << P);
        const float a0r = ar[i0], a0i = ai[i0], a1r = ar[i1], a1i = ai[i1];
        ar[i0] = c * a0r - s * a1r;
        ai[i0] = c * a0i - s * a1i;
        ar[i1] = s * a0r + c * a1r;
        ai[i1] = s * a0i + c * a1i;
    }
}

template<int PC, int PT>
__device__ __forceinline__ void cnot_gate(float (&ar)[16], float (&ai)[16]) {
#pragma unroll
    for (int i = 0; i < 16; ++i) {
        if ((i & (1 << PC)) && !(i & (1 << PT))) {
            const int j = i | (1 << PT);
            float tr = ar[i]; ar[i] = ar[j]; ar[j] = tr;
            float ti = ai[i]; ai[i] = ai[j]; ai[j] = ti;
        }
    }
}

// pack-reduce: s0..s3 (per-lane partials) -> lane j in {0..3} holds total s_j.
// 7 shfls total: 2-level 4x4 transpose-combine + 4-level butterfly.
__device__ __forceinline__ float pack_reduce4(int lane, float s0, float s1, float s2, float s3) {
    const bool b1 = (lane & 1) != 0;
    const bool b2 = (lane & 2) != 0;
    const float u01 = (b1 ? s1 : s0) + __shfl_xor(b1 ? s0 : s1, 1);
    const float u23 = (b1 ? s3 : s2) + __shfl_xor(b1 ? s2 : s3, 1);
    float v = (b2 ? u23 : u01) + __shfl_xor(b2 ? u01 : u23, 2);
    v += __shfl_xor(v, 4);
    v += __shfl_xor(v, 8);
    v += __shfl_xor(v, 16);
    v += __shfl_xor(v, 32);
    return v;  // lane&3 == j  =>  v = total s_j
}

__global__ __launch_bounds__(256, 4)
void hybrid_qnn_kernel(const float* __restrict__ x,
                       const float* __restrict__ W_red,
                       const float* __restrict__ b_red,
                       const float* __restrict__ qw,
                       const float* __restrict__ W_out,
                       const float* __restrict__ b_out,
                       float* __restrict__ out,
                       int B)
{
    __shared__ float h_lds[64][4];
    __shared__ float qc_lds[8];
    __shared__ float qs_lds[8];
    __shared__ float outStage[640];

    const int t = threadIdx.x;
    const int lane = t & 63;
    const int wave = t >> 6;
    const long long blockBase = (long long)blockIdx.x * 64;
    const long long wbase = blockBase + wave * 16;

    if (t < 8) {
        const float a = 0.5f * qw[t];
        qc_lds[t] = cosf(a);
        qs_lds[t] = sinf(a);
    }

    const float inv255 = 1.0f / 255.0f;

    // ---- main weights (floats 0..767), split-K over 64 lanes, pre-scaled ----
    float4 Wl[3][4];
#pragma unroll
    for (int c = 0; c < 3; ++c) {
#pragma unroll
        for (int j = 0; j < 4; ++j) {
            const float4 w = *(const float4*)(W_red + j * 784 + 4 * (lane + 64 * c));
            Wl[c][j] = make_float4(w.x * inv255, w.y * inv255, w.z * inv255, w.w * inv255);
        }
    }
    const float br0 = b_red[0], br1 = b_red[1], br2 = b_red[2], br3 = b_red[3];

    // ---- tail prepass: floats 768..783 for this wave's 16 samples ----
    // lane = s*4 + c : sample s (0..15), chunk c (0..3)
    {
        const int s = lane >> 2;
        const int c = lane & 3;
        const long long samp = wbase + s;
        float4 wt[4];
#pragma unroll
        for (int j = 0; j < 4; ++j) {
            const float4 w = *(const float4*)(W_red + j * 784 + 768 + 4 * c);
            wt[j] = make_float4(w.x * inv255, w.y * inv255, w.z * inv255, w.w * inv255);
        }
        float4 xt = make_float4(0.f, 0.f, 0.f, 0.f);
        if (samp < B) xt = *(const float4*)(x + (size_t)samp * 784 + 768 + 4 * c);
        float d0 = dot4(xt, wt[0]);
        float d1 = dot4(xt, wt[1]);
        float d2 = dot4(xt, wt[2]);
        float d3 = dot4(xt, wt[3]);
        // reduce over c (lane bits 0..1)
        d0 += __shfl_xor(d0, 1); d0 += __shfl_xor(d0, 2);
        d1 += __shfl_xor(d1, 1); d1 += __shfl_xor(d1, 2);
        d2 += __shfl_xor(d2, 1); d2 += __shfl_xor(d2, 2);
        d3 += __shfl_xor(d3, 1); d3 += __shfl_xor(d3, 2);
        if (c == 0 && samp < B) {
            const int srow = wave * 16 + s;
            h_lds[srow][0] = d0 + br0;
            h_lds[srow][1] = d1 + br1;
            h_lds[srow][2] = d2 + br2;
            h_lds[srow][3] = d3 + br3;
        }
    }

    // ---- phase A: 3 coalesced 1KB loads/sample, depth-2 software pipeline ----
    if (wbase + 16 <= B) {
        const float* xbase = x + (size_t)wbase * 784;
        // stage A = sample 0, stage B = sample 1
        float4 a0 = *(const float4*)(xbase + 4 * lane);
        float4 a1 = *(const float4*)(xbase + 4 * (lane + 64));
        float4 a2 = *(const float4*)(xbase + 4 * (lane + 128));
        float4 b0 = *(const float4*)(xbase + 784 + 4 * lane);
        float4 b1 = *(const float4*)(xbase + 784 + 4 * (lane + 64));
        float4 b2 = *(const float4*)(xbase + 784 + 4 * (lane + 128));
#pragma unroll
        for (int q = 0; q < 16; ++q) {
            const float4 x0 = a0, x1 = a1, x2 = a2;
            a0 = b0; a1 = b1; a2 = b2;
            if (q + 2 < 16) {
                const float* nb = xbase + (size_t)(q + 2) * 784;
                b0 = *(const float4*)(nb + 4 * lane);
                b1 = *(const float4*)(nb + 4 * (lane + 64));
                b2 = *(const float4*)(nb + 4 * (lane + 128));
            }
            const float s0 = dot4(x0, Wl[0][0]) + dot4(x1, Wl[1][0]) + dot4(x2, Wl[2][0]);
            const float s1 = dot4(x0, Wl[0][1]) + dot4(x1, Wl[1][1]) + dot4(x2, Wl[2][1]);
            const float s2 = dot4(x0, Wl[0][2]) + dot4(x1, Wl[1][2]) + dot4(x2, Wl[2][2]);
            const float s3 = dot4(x0, Wl[0][3]) + dot4(x1, Wl[1][3]) + dot4(x2, Wl[2][3]);
            const float v = pack_reduce4(lane, s0, s1, s2, s3);
            if (lane < 4) h_lds[wave * 16 + q][lane] += v;
        }
    } else {
        for (int q = 0; q < 16; ++q) {
            const long long samp = wbase + q;
            if (samp >= B) break;
            const float* xb = x + (size_t)samp * 784;
            const float4 x0 = *(const float4*)(xb + 4 * lane);
            const float4 x1 = *(const float4*)(xb + 4 * (lane + 64));
            const float4 x2 = *(const float4*)(xb + 4 * (lane + 128));
            const float s0 = dot4(x0, Wl[0][0]) + dot4(x1, Wl[1][0]) + dot4(x2, Wl[2][0]);
            const float s1 = dot4(x0, Wl[0][1]) + dot4(x1, Wl[1][1]) + dot4(x2, Wl[2][1]);
            const float s2 = dot4(x0, Wl[0][2]) + dot4(x1, Wl[1][2]) + dot4(x2, Wl[2][2]);
            const float s3 = dot4(x0, Wl[0][3]) + dot4(x1, Wl[1][3]) + dot4(x2, Wl[2][3]);
            const float v = pack_reduce4(lane, s0, s1, s2, s3);
            if (lane < 4) h_lds[wave * 16 + q][lane] += v;
        }
    }
    __syncthreads();

    // ---- phase B: per-thread 4-qubit statevector sim for one sample ----
    if (t < 64 && blockBase + t < B) {
        const float ang0 = tanhf(h_lds[t][0]) * PI_F;
        const float ang1 = tanhf(h_lds[t][1]) * PI_F;
        const float ang2 = tanhf(h_lds[t][2]) * PI_F;
        const float ang3 = tanhf(h_lds[t][3]) * PI_F;
        const float c0 = cosf(0.5f * ang0), sn0 = sinf(0.5f * ang0);
        const float c1 = cosf(0.5f * ang1), sn1 = sinf(0.5f * ang1);
        const float c2 = cosf(0.5f * ang2), sn2 = sinf(0.5f * ang2);
        const float c3 = cosf(0.5f * ang3), sn3 = sinf(0.5f * ang3);

        float ar[16], ai[16];
#pragma unroll
        for (int i = 0; i < 16; ++i) { ar[i] = 0.f; ai[i] = 0.f; }
        ar[0] = 1.f;

        // RX encoding: wire w -> bit position 3-w (wire 0 = MSB)
        rx_gate<3>(ar, ai, c0, sn0);
        rx_gate<2>(ar, ai, c1, sn1);
        rx_gate<1>(ar, ai, c2, sn2);
        rx_gate<0>(ar, ai, c3, sn3);

#pragma unroll
        for (int layer = 0; layer < 2; ++layer) {
            const int k0 = layer * 4;
            ry_gate<3>(ar, ai, qc_lds[k0 + 0], qs_lds[k0 + 0]);
            ry_gate<2>(ar, ai, qc_lds[k0 + 1], qs_lds[k0 + 1]);
            ry_gate<1>(ar, ai, qc_lds[k0 + 2], qs_lds[k0 + 2]);
            ry_gate<0>(ar, ai, qc_lds[k0 + 3], qs_lds[k0 + 3]);
            // CNOT ring (control wire, target wire): (0,1),(1,2),(2,3),(3,0)
            cnot_gate<3, 2>(ar, ai);
            cnot_gate<2, 1>(ar, ai);
            cnot_gate<1, 0>(ar, ai);
            cnot_gate<0, 3>(ar, ai);
        }

        float pr[16];
#pragma unroll
        for (int i = 0; i < 16; ++i) pr[i] = ar[i] * ar[i] + ai[i] * ai[i];

        float ev[4];
#pragma unroll
        for (int w = 0; w < 4; ++w) {
            const int p = 3 - w;
            float e = 0.f;
#pragma unroll
            for (int i = 0; i < 16; ++i) e += (i & (1 << p)) ? -pr[i] : pr[i];
            ev[w] = e;
        }

#pragma unroll
        for (int n = 0; n < 10; ++n) {
            float o = b_out[n];
#pragma unroll
            for (int j = 0; j < 4; ++j) o += ev[j] * W_out[n * 4 + j];
            outStage[t * 10 + n] = o;
        }
    }
    __syncthreads();

    // ---- coalesced output store ----
    const long long outBase = (long long)blockIdx.x * 640;
    const long long outTotal = (long long)B * 10;
#pragma unroll
    for (int i = t; i < 640; i += 256) {
        const long long oi = outBase + i;
        if (oi < outTotal) out[oi] = outStage[i];
    }
}

extern "C" void kernel_launch(void* const* d_in, const int* in_sizes, int n_in,
                              void* d_out, int out_size, void* d_ws, size_t ws_size,
                              hipStream_t stream) {
    const float* x      = (const float*)d_in[0];
    const float* W_red  = (const float*)d_in[1];
    const float* b_red  = (const float*)d_in[2];
    const float* qw     = (const float*)d_in[3];
    const float* W_out  = (const float*)d_in[4];
    const float* b_out  = (const float*)d_in[5];
    float* out = (float*)d_out;

    const int B = in_sizes[0] / 784;
    const int grid = (B + 63) / 64;
    hipLaunchKernelGGL(hybrid_qnn_kernel, dim3(grid), dim3(256), 0, stream,
                       x, W_red, b_red, qw, W_out, b_out, out, B);
}